// Round 3
// baseline (12760.716 us; speedup 1.0000x reference)
//
#include <hip/hip_runtime.h>
#include <stdint.h>

// World model v3: device I/O is FLOAT32 (ref outputs are f32; expected npz is
// bf16-ized only for transfer -> threshold 163.84 = 2%*bf16(8191)).
// d_in[0]=z f32[16384*64], d_in[1]=emb f32[8192*64],
// d_out = f32: [z_q 16384*64][idx-as-float 16384].
// Replicate numpy f32 bit-exactly:
//   sz,se: scalar pairwise-8 (squares rounded separately)
//   c: einsum SOP baseline SSE: 4 lanes (k mod 4), mul+add (no fma),
//      x4-unrolled REVERSED chunk chain (+12,+8,+4,+0), hadd: (q0+q1)+(q2+q3)
//   A=fl(sz+se); d=fl(A-2c); argmin strict-<, first index wins ties.

#define NROWS 16384
#define NE    8192
#define D     64
#define RPB   16
#define NT    256
#define NTILES (NE / NT)

__global__ void vq_sentinel(float* __restrict__ out) {
    int i = blockIdx.x * blockDim.x + threadIdx.x;
    if (i < NROWS) out[(size_t)NROWS * D + i] = 3.0f;
}

__global__ __launch_bounds__(NT)
void vq_main(const float* __restrict__ z, const float* __restrict__ e,
             float* __restrict__ out)
{
    __shared__ float zf[RPB][D];
    __shared__ float szs[RPB];
    __shared__ float wd[RPB][4];
    __shared__ int   wj[RPB][4];
    __shared__ int   bsel[RPB];

    const int t    = threadIdx.x;
    const int lane = t & 63;
    const int wave = t >> 6;
    const int row0 = blockIdx.x * RPB;

    for (int m = t; m < RPB * D; m += NT)
        zf[m >> 6][m & 63] = z[(size_t)row0 * D + m];
    __syncthreads();

    // sz = np.sum(z**2, axis=1): scalar pairwise-8
    if (t < RPB) {
        float r8[8];
        #pragma unroll
        for (int l = 0; l < 8; ++l) r8[l] = __fmul_rn(zf[t][l], zf[t][l]);
        #pragma unroll
        for (int i = 8; i < 64; i += 8)
            #pragma unroll
            for (int l = 0; l < 8; ++l)
                r8[l] = __fadd_rn(r8[l], __fmul_rn(zf[t][i + l], zf[t][i + l]));
        szs[t] = __fadd_rn(__fadd_rn(__fadd_rn(r8[0], r8[1]), __fadd_rn(r8[2], r8[3])),
                           __fadd_rn(__fadd_rn(r8[4], r8[5]), __fadd_rn(r8[6], r8[7])));
    }
    __syncthreads();

    float bd[RPB]; int bj[RPB];
    #pragma unroll
    for (int r = 0; r < RPB; ++r) { bd[r] = 3.0e38f; bj[r] = 0; }

    for (int tile = 0; tile < NTILES; ++tile) {
        const int j = tile * NT + t;
        const float* er = e + (size_t)j * D;
        float ef[D];
        #pragma unroll
        for (int c4 = 0; c4 < D / 4; ++c4) {
            const float4 v = *reinterpret_cast<const float4*>(er + c4 * 4);
            ef[c4 * 4 + 0] = v.x; ef[c4 * 4 + 1] = v.y;
            ef[c4 * 4 + 2] = v.z; ef[c4 * 4 + 3] = v.w;
        }
        // se = np.sum(e**2, axis=1): scalar pairwise-8
        float r8[8];
        #pragma unroll
        for (int l = 0; l < 8; ++l) r8[l] = __fmul_rn(ef[l], ef[l]);
        #pragma unroll
        for (int i = 8; i < 64; i += 8)
            #pragma unroll
            for (int l = 0; l < 8; ++l)
                r8[l] = __fadd_rn(r8[l], __fmul_rn(ef[i + l], ef[i + l]));
        const float se = __fadd_rn(__fadd_rn(__fadd_rn(r8[0], r8[1]), __fadd_rn(r8[2], r8[3])),
                                   __fadd_rn(__fadd_rn(r8[4], r8[5]), __fadd_rn(r8[6], r8[7])));

        #pragma unroll
        for (int r = 0; r < RPB; ++r) {
            const float A = __fadd_rn(szs[r], se);   // fl(sz + se)
            // einsum SOP: lane l accumulates k===l (mod 4); chunks of 16 ascending,
            // within chunk reversed sub-blocks (+12, +8, +4, +0); mul+add separately rounded.
            float q0 = 0.f, q1 = 0.f, q2 = 0.f, q3 = 0.f;
            #pragma unroll
            for (int cc = 0; cc < 4; ++cc) {
                const int b = cc * 16;
                q0 = __fadd_rn(q0, __fmul_rn(zf[r][b + 12], ef[b + 12]));
                q1 = __fadd_rn(q1, __fmul_rn(zf[r][b + 13], ef[b + 13]));
                q2 = __fadd_rn(q2, __fmul_rn(zf[r][b + 14], ef[b + 14]));
                q3 = __fadd_rn(q3, __fmul_rn(zf[r][b + 15], ef[b + 15]));
                q0 = __fadd_rn(q0, __fmul_rn(zf[r][b +  8], ef[b +  8]));
                q1 = __fadd_rn(q1, __fmul_rn(zf[r][b +  9], ef[b +  9]));
                q2 = __fadd_rn(q2, __fmul_rn(zf[r][b + 10], ef[b + 10]));
                q3 = __fadd_rn(q3, __fmul_rn(zf[r][b + 11], ef[b + 11]));
                q0 = __fadd_rn(q0, __fmul_rn(zf[r][b +  4], ef[b +  4]));
                q1 = __fadd_rn(q1, __fmul_rn(zf[r][b +  5], ef[b +  5]));
                q2 = __fadd_rn(q2, __fmul_rn(zf[r][b +  6], ef[b +  6]));
                q3 = __fadd_rn(q3, __fmul_rn(zf[r][b +  7], ef[b +  7]));
                q0 = __fadd_rn(q0, __fmul_rn(zf[r][b +  0], ef[b +  0]));
                q1 = __fadd_rn(q1, __fmul_rn(zf[r][b +  1], ef[b +  1]));
                q2 = __fadd_rn(q2, __fmul_rn(zf[r][b +  2], ef[b +  2]));
                q3 = __fadd_rn(q3, __fmul_rn(zf[r][b +  3], ef[b +  3]));
            }
            // npyv_sum via SSE3 hadd: (q0+q1) + (q2+q3)
            const float c = __fadd_rn(__fadd_rn(q0, q1), __fadd_rn(q2, q3));
            const float dd = __fsub_rn(A, __fadd_rn(c, c));   // fl(A - 2c), 2c exact
            if (dd < bd[r]) { bd[r] = dd; bj[r] = j; }        // first (smallest) j wins
        }
    }

    // wave-level argmin (64 lanes), then cross-wave combine; smaller j on ties
    #pragma unroll 1
    for (int r = 0; r < RPB; ++r) {
        float d = bd[r]; int j = bj[r];
        #pragma unroll
        for (int off = 1; off < 64; off <<= 1) {
            const float od = __shfl_xor(d, off, 64);
            const int   oj = __shfl_xor(j, off, 64);
            if (od < d || (od == d && oj < j)) { d = od; j = oj; }
        }
        if (lane == 0) { wd[r][wave] = d; wj[r][wave] = j; }
    }
    __syncthreads();

    if (t < RPB) {
        float d = wd[t][0]; int j = wj[t][0];
        #pragma unroll
        for (int w = 1; w < 4; ++w) {
            const float od = wd[t][w]; const int oj = wj[t][w];
            if (od < d || (od == d && oj < j)) { d = od; j = oj; }
        }
        bsel[t] = j;
        out[(size_t)NROWS * D + row0 + t] = (float)j;   // idx as float32
    }
    __syncthreads();

    // z_q = fl(z + fl(e[idx] - z))
    for (int m = t; m < RPB * D; m += NT) {
        const int r = m >> 6, k = m & 63;
        const float zv = zf[r][k];
        const float ev = e[(size_t)bsel[r] * D + k];
        out[(size_t)row0 * D + m] = __fadd_rn(zv, __fsub_rn(ev, zv));
    }
}

extern "C" void kernel_launch(void* const* d_in, const int* in_sizes, int n_in,
                              void* d_out, int out_size, void* d_ws, size_t ws_size,
                              hipStream_t stream)
{
    const float* z = (const float*)d_in[0];
    const float* e = (const float*)d_in[1];
    float* out = (float*)d_out;

    vq_sentinel<<<dim3((NROWS + 255) / 256), dim3(256), 0, stream>>>(out);
    vq_main<<<dim3(NROWS / RPB), dim3(NT), 0, stream>>>(z, e, out);
}

// Round 4
// 449.419 us; speedup vs baseline: 28.3938x; 28.3938x over previous
//
#include <hip/hip_runtime.h>
#include <stdint.h>

// VectorQuantizer, world model CONFIRMED (round 3 absmax 0.0):
//   f32 I/O. d_in[0]=z [16384,64], d_in[1]=e [8192,64].
//   d_out f32: [z_q 16384*64][idx-as-float 16384].
// Frozen numerics (bit-exact numpy replication):
//   sz,se: scalar pairwise-8 (squares rounded separately)
//   c: 4 accum lanes (k mod 4), mul+add separately rounded, 16-chunks ascending,
//      sub-blocks within chunk REVERSED (+12,+8,+4,+0), hadd (q0+q1)+(q2+q3)
//   A=fl(sz+se); d=fl(A-2c); argmin strict-<, first (smallest) index wins.
//
// Round-4 restructure for perf (round 3: VALUBusy 2%, VGPR 256, 14.7GB spill
// traffic): one row per thread (z in VGPRs), j-space split in 16 chunks,
// e-row reads are wave-uniform -> scalar s_loads (SGPRs, no spills).
// Temp storage lives inside d_out (se in idx region; chunk partials in z_q
// region slots 0..31), all overwritten by later phases. No workspace.

#define NROWS 16384
#define NE    8192
#define D     64
#define NCHUNK 16
#define JPC   (NE / NCHUNK)   // 512

__device__ __forceinline__ float sumsq_pairwise8(const float* x) {
    float r8[8];
    #pragma unroll
    for (int l = 0; l < 8; ++l) r8[l] = __fmul_rn(x[l], x[l]);
    #pragma unroll
    for (int i = 8; i < 64; i += 8)
        #pragma unroll
        for (int l = 0; l < 8; ++l)
            r8[l] = __fadd_rn(r8[l], __fmul_rn(x[i + l], x[i + l]));
    return __fadd_rn(__fadd_rn(__fadd_rn(r8[0], r8[1]), __fadd_rn(r8[2], r8[3])),
                     __fadd_rn(__fadd_rn(r8[4], r8[5]), __fadd_rn(r8[6], r8[7])));
}

// Phase 1: se[j] into idx region of out (overwritten by phase 3 later).
__global__ __launch_bounds__(256)
void vq_se(const float* __restrict__ e, float* __restrict__ out) {
    const int j = blockIdx.x * 256 + threadIdx.x;
    if (j >= NE) return;
    const float* er = e + (size_t)j * D;
    float ef[D];
    #pragma unroll
    for (int k = 0; k < D; ++k) ef[k] = er[k];
    out[(size_t)NROWS * D + j] = sumsq_pairwise8(ef);
}

// Phase 2: scan. block = (row-block rb, chunk jc); thread owns one row.
__global__ __launch_bounds__(256)
void vq_scan(const float* __restrict__ z, const float* __restrict__ e,
             float* __restrict__ out) {
    const int rb  = blockIdx.x & 63;        // 64 row-blocks
    const int jc  = blockIdx.x >> 6;        // 16 chunks; consecutive bids share jc
    const int row = rb * 256 + threadIdx.x;

    float zr[D];
    {
        const float* zrow = z + (size_t)row * D;
        #pragma unroll
        for (int k = 0; k < D; ++k) zr[k] = zrow[k];
    }
    const float sz = sumsq_pairwise8(zr);
    const float* __restrict__ se_arr = out + (size_t)NROWS * D;

    float bd = 3.0e38f;
    int   bj = 0;
    const int j0 = jc * JPC;

    #pragma unroll 1
    for (int j = j0; j < j0 + JPC; ++j) {
        // e-row address is wave-uniform -> scalar loads (SGPRs)
        const float* er = e + (size_t)j * D;
        float ef[D];
        #pragma unroll
        for (int k = 0; k < D; ++k) ef[k] = er[k];

        const float A = __fadd_rn(sz, se_arr[j]);   // fl(sz + se)

        float q0 = 0.f, q1 = 0.f, q2 = 0.f, q3 = 0.f;
        #pragma unroll
        for (int cc = 0; cc < 4; ++cc) {
            const int b = cc * 16;
            q0 = __fadd_rn(q0, __fmul_rn(zr[b + 12], ef[b + 12]));
            q1 = __fadd_rn(q1, __fmul_rn(zr[b + 13], ef[b + 13]));
            q2 = __fadd_rn(q2, __fmul_rn(zr[b + 14], ef[b + 14]));
            q3 = __fadd_rn(q3, __fmul_rn(zr[b + 15], ef[b + 15]));
            q0 = __fadd_rn(q0, __fmul_rn(zr[b +  8], ef[b +  8]));
            q1 = __fadd_rn(q1, __fmul_rn(zr[b +  9], ef[b +  9]));
            q2 = __fadd_rn(q2, __fmul_rn(zr[b + 10], ef[b + 10]));
            q3 = __fadd_rn(q3, __fmul_rn(zr[b + 11], ef[b + 11]));
            q0 = __fadd_rn(q0, __fmul_rn(zr[b +  4], ef[b +  4]));
            q1 = __fadd_rn(q1, __fmul_rn(zr[b +  5], ef[b +  5]));
            q2 = __fadd_rn(q2, __fmul_rn(zr[b +  6], ef[b +  6]));
            q3 = __fadd_rn(q3, __fmul_rn(zr[b +  7], ef[b +  7]));
            q0 = __fadd_rn(q0, __fmul_rn(zr[b +  0], ef[b +  0]));
            q1 = __fadd_rn(q1, __fmul_rn(zr[b +  1], ef[b +  1]));
            q2 = __fadd_rn(q2, __fmul_rn(zr[b +  2], ef[b +  2]));
            q3 = __fadd_rn(q3, __fmul_rn(zr[b +  3], ef[b +  3]));
        }
        const float c  = __fadd_rn(__fadd_rn(q0, q1), __fadd_rn(q2, q3));
        const float dd = __fsub_rn(A, __fadd_rn(c, c));   // fl(A - 2c)
        if (dd < bd) { bd = dd; bj = j; }                 // ascending j: first wins
    }

    // chunk partials into z_q region slots (overwritten by phase 4)
    out[(size_t)row * D + jc] = bd;
    reinterpret_cast<uint32_t*>(out)[(size_t)row * D + 16 + jc] = (uint32_t)bj;
}

// Phase 3: reduce 16 chunk partials per row (ascending chunk, strict-< ->
// global first-min); write idx-as-float into idx region.
__global__ __launch_bounds__(256)
void vq_reduce(float* __restrict__ out) {
    const int row = blockIdx.x * 256 + threadIdx.x;
    if (row >= NROWS) return;
    const float*    dr = out + (size_t)row * D;
    const uint32_t* jr = reinterpret_cast<const uint32_t*>(out) + (size_t)row * D + 16;
    float bd = dr[0];
    int   bj = (int)jr[0];
    #pragma unroll
    for (int c = 1; c < NCHUNK; ++c) {
        const float d2 = dr[c];
        if (d2 < bd) { bd = d2; bj = (int)jr[c]; }
    }
    out[(size_t)NROWS * D + row] = (float)bj;
}

// Phase 4: z_q = fl(z + fl(e[idx] - z)) elementwise, reading idx from out.
__global__ __launch_bounds__(256)
void vq_zq(const float* __restrict__ z, const float* __restrict__ e,
           float* __restrict__ out) {
    const size_t m = (size_t)blockIdx.x * 256 + threadIdx.x;
    if (m >= (size_t)NROWS * D) return;
    const int r = (int)(m >> 6), k = (int)(m & 63);
    const int sel = (int)out[(size_t)NROWS * D + r];
    const float zv = z[m];
    const float ev = e[(size_t)sel * D + k];
    out[m] = __fadd_rn(zv, __fsub_rn(ev, zv));
}

extern "C" void kernel_launch(void* const* d_in, const int* in_sizes, int n_in,
                              void* d_out, int out_size, void* d_ws, size_t ws_size,
                              hipStream_t stream)
{
    const float* z = (const float*)d_in[0];
    const float* e = (const float*)d_in[1];
    float* out = (float*)d_out;

    vq_se    <<<dim3(NE / 256),          dim3(256), 0, stream>>>(e, out);
    vq_scan  <<<dim3(64 * NCHUNK),       dim3(256), 0, stream>>>(z, e, out);
    vq_reduce<<<dim3(NROWS / 256),       dim3(256), 0, stream>>>(out);
    vq_zq    <<<dim3(NROWS * D / 256),   dim3(256), 0, stream>>>(z, e, out);
}

// Round 5
// 430.560 us; speedup vs baseline: 29.6375x; 1.0438x over previous
//
#include <hip/hip_runtime.h>
#include <stdint.h>

// VectorQuantizer — world model CONFIRMED: f32 I/O.
// d_in[0]=z [16384,64], d_in[1]=e [8192,64]; d_out f32 [z_q 16384*64][idx 16384].
// FROZEN exact numerics (used only in rescore):
//   sz,se: scalar pairwise-8; c: 4 lanes (k mod 4), mul/add separately rounded,
//   16-chunks ascending with reversed sub-blocks (+12,+8,+4,+0), hadd (q0+q1)+(q2+q3);
//   A=fl(sz+se); d=fl(A-2c); argmin strict-<, first (smallest) index wins.
// Round-5: FMA prefilter scan (top-4 c per row-chunk) + exact rescore of
// candidates within 2e-5 of row-max c (provable 9e-6 slack; 2.2x margin).

#define NROWS 16384
#define NE    8192
#define D     64
#define RESCORE_DELTA 2.0e-5f

struct Rec { float c[4]; int j[4]; };   // 32 B

// ---------- frozen exact helpers ----------
__device__ __forceinline__ float sumsq_pairwise8(const float* x) {
    float r8[8];
    #pragma unroll
    for (int l = 0; l < 8; ++l) r8[l] = __fmul_rn(x[l], x[l]);
    #pragma unroll
    for (int i = 8; i < 64; i += 8)
        #pragma unroll
        for (int l = 0; l < 8; ++l)
            r8[l] = __fadd_rn(r8[l], __fmul_rn(x[i + l], x[i + l]));
    return __fadd_rn(__fadd_rn(__fadd_rn(r8[0], r8[1]), __fadd_rn(r8[2], r8[3])),
                     __fadd_rn(__fadd_rn(r8[4], r8[5]), __fadd_rn(r8[6], r8[7])));
}

__device__ __forceinline__ float dot_numpy(const float* zr, const float* ef) {
    float q0 = 0.f, q1 = 0.f, q2 = 0.f, q3 = 0.f;
    #pragma unroll
    for (int cc = 0; cc < 4; ++cc) {
        const int b = cc * 16;
        q0 = __fadd_rn(q0, __fmul_rn(zr[b + 12], ef[b + 12]));
        q1 = __fadd_rn(q1, __fmul_rn(zr[b + 13], ef[b + 13]));
        q2 = __fadd_rn(q2, __fmul_rn(zr[b + 14], ef[b + 14]));
        q3 = __fadd_rn(q3, __fmul_rn(zr[b + 15], ef[b + 15]));
        q0 = __fadd_rn(q0, __fmul_rn(zr[b +  8], ef[b +  8]));
        q1 = __fadd_rn(q1, __fmul_rn(zr[b +  9], ef[b +  9]));
        q2 = __fadd_rn(q2, __fmul_rn(zr[b + 10], ef[b + 10]));
        q3 = __fadd_rn(q3, __fmul_rn(zr[b + 11], ef[b + 11]));
        q0 = __fadd_rn(q0, __fmul_rn(zr[b +  4], ef[b +  4]));
        q1 = __fadd_rn(q1, __fmul_rn(zr[b +  5], ef[b +  5]));
        q2 = __fadd_rn(q2, __fmul_rn(zr[b +  6], ef[b +  6]));
        q3 = __fadd_rn(q3, __fmul_rn(zr[b +  7], ef[b +  7]));
        q0 = __fadd_rn(q0, __fmul_rn(zr[b +  0], ef[b +  0]));
        q1 = __fadd_rn(q1, __fmul_rn(zr[b +  1], ef[b +  1]));
        q2 = __fadd_rn(q2, __fmul_rn(zr[b +  2], ef[b +  2]));
        q3 = __fadd_rn(q3, __fmul_rn(zr[b +  3], ef[b +  3]));
    }
    return __fadd_rn(__fadd_rn(q0, q1), __fadd_rn(q2, q3));
}

// ---------- phase 1: FMA prefilter, top-4 c per (row, chunk) ----------
template<int NCHUNK>
__global__ __launch_bounds__(256)
void vq_scan_fma(const float* __restrict__ z, const float* __restrict__ e,
                 Rec* __restrict__ recs)
{
    constexpr int JPC = NE / NCHUNK;
    const int rb  = blockIdx.x & 63;          // 64 row-blocks of 256 rows
    const int jc  = blockIdx.x >> 6;          // chunk id
    const int row = rb * 256 + threadIdx.x;

    float zr[D];
    {
        const float* zrow = z + (size_t)row * D;
        #pragma unroll
        for (int k = 0; k < D; ++k) zr[k] = zrow[k];
    }
    // pin zr in VGPRs; block re-materialization (round-4 VGPR=40 symptom)
    #pragma unroll
    for (int k = 0; k < D; ++k) asm volatile("" : "+v"(zr[k]));

    float b0 = -3.0e38f, b1 = -3.0e38f, b2 = -3.0e38f, b3 = -3.0e38f;
    int   i0 = 0, i1 = 0, i2 = 0, i3 = 0;

    const int jbase = jc * JPC;
    #pragma unroll 1
    for (int j = jbase; j < jbase + JPC; ++j) {
        const float* er = e + (size_t)j * D;   // wave-uniform -> scalar loads
        float ef[D];
        #pragma unroll
        for (int k = 0; k < D; ++k) ef[k] = er[k];

        float q0 = 0.f, q1 = 0.f, q2 = 0.f, q3 = 0.f;
        #pragma unroll
        for (int k = 0; k < D; k += 4) {
            q0 = fmaf(zr[k + 0], ef[k + 0], q0);
            q1 = fmaf(zr[k + 1], ef[k + 1], q1);
            q2 = fmaf(zr[k + 2], ef[k + 2], q2);
            q3 = fmaf(zr[k + 3], ef[k + 3], q3);
        }
        const float c = (q0 + q1) + (q2 + q3);

        if (c > b3) {   // stable strict-> insert: equal c keeps earlier j first
            if (c > b0)      { b3=b2; i3=i2; b2=b1; i2=i1; b1=b0; i1=i0; b0=c; i0=j; }
            else if (c > b1) { b3=b2; i3=i2; b2=b1; i2=i1; b1=c; i1=j; }
            else if (c > b2) { b3=b2; i3=i2; b2=c; i2=j; }
            else             { b3=c; i3=j; }
        }
    }

    Rec r;
    r.c[0] = b0; r.c[1] = b1; r.c[2] = b2; r.c[3] = b3;
    r.j[0] = i0; r.j[1] = i1; r.j[2] = i2; r.j[3] = i3;
    recs[(size_t)row * NCHUNK + jc] = r;
}

// ---------- phase 2: exact rescore of near-max candidates ----------
template<int NCHUNK>
__global__ __launch_bounds__(256)
void vq_rescore(const float* __restrict__ z, const float* __restrict__ e,
                const Rec* __restrict__ recs, float* __restrict__ out)
{
    const int row = blockIdx.x * 256 + threadIdx.x;
    const Rec* rr = recs + (size_t)row * NCHUNK;

    float cm = -3.0e38f;
    #pragma unroll 1
    for (int ch = 0; ch < NCHUNK; ++ch) {
        #pragma unroll
        for (int s = 0; s < 4; ++s) cm = fmaxf(cm, rr[ch].c[s]);
    }
    const float thr = cm - RESCORE_DELTA;

    float zr[D];
    {
        const float* zrow = z + (size_t)row * D;
        #pragma unroll
        for (int k = 0; k < D; ++k) zr[k] = zrow[k];
    }
    const float sz = sumsq_pairwise8(zr);

    float bd = 3.0e38f; int bj = 0x7fffffff;
    #pragma unroll 1
    for (int ch = 0; ch < NCHUNK; ++ch) {
        #pragma unroll 1
        for (int s = 0; s < 4; ++s) {
            const float cf = rr[ch].c[s];
            const int   j  = rr[ch].j[s];
            if (cf >= thr) {
                float ef[D];
                const float* er = e + (size_t)j * D;
                #pragma unroll
                for (int k = 0; k < D; ++k) ef[k] = er[k];
                const float se = sumsq_pairwise8(ef);
                const float A  = __fadd_rn(sz, se);          // fl(sz + se)
                const float c  = dot_numpy(zr, ef);          // exact numpy order
                const float d  = __fsub_rn(A, __fadd_rn(c, c)); // fl(A - 2c)
                if (d < bd || (d == bd && j < bj)) { bd = d; bj = j; }
            }
        }
    }
    out[(size_t)NROWS * D + row] = (float)bj;
}

// ---------- phase 3: z_q = fl(z + fl(e[idx] - z)) ----------
__global__ __launch_bounds__(256)
void vq_zq(const float* __restrict__ z, const float* __restrict__ e,
           float* __restrict__ out)
{
    const size_t m = (size_t)blockIdx.x * 256 + threadIdx.x;
    const int r = (int)(m >> 6), k = (int)(m & 63);
    const int sel = (int)out[(size_t)NROWS * D + r];
    const float zv = z[m];
    const float ev = e[(size_t)sel * D + k];
    out[m] = __fadd_rn(zv, __fsub_rn(ev, zv));
}

extern "C" void kernel_launch(void* const* d_in, const int* in_sizes, int n_in,
                              void* d_out, int out_size, void* d_ws, size_t ws_size,
                              hipStream_t stream)
{
    const float* z = (const float*)d_in[0];
    const float* e = (const float*)d_in[1];
    float* out = (float*)d_out;

    const size_t need32 = (size_t)NROWS * 32 * sizeof(Rec);   // 16 MB
    const size_t need16 = (size_t)NROWS * 16 * sizeof(Rec);   //  8 MB

    if (ws_size >= need32) {
        Rec* recs = (Rec*)d_ws;
        vq_scan_fma<32><<<dim3(64 * 32), dim3(256), 0, stream>>>(z, e, recs);
        vq_rescore<32><<<dim3(NROWS / 256), dim3(256), 0, stream>>>(z, e, recs, out);
    } else if (ws_size >= need16) {
        Rec* recs = (Rec*)d_ws;
        vq_scan_fma<16><<<dim3(64 * 16), dim3(256), 0, stream>>>(z, e, recs);
        vq_rescore<16><<<dim3(NROWS / 256), dim3(256), 0, stream>>>(z, e, recs, out);
    } else {
        // scratch = z_q region of d_out: 16384*8*32 B = 4 MB exactly; overwritten by vq_zq
        Rec* recs = (Rec*)out;
        vq_scan_fma<8><<<dim3(64 * 8), dim3(256), 0, stream>>>(z, e, recs);
        vq_rescore<8><<<dim3(NROWS / 256), dim3(256), 0, stream>>>(z, e, recs, out);
    }
    vq_zq<<<dim3(NROWS * D / 256), dim3(256), 0, stream>>>(z, e, out);
}

// Round 6
// 234.266 us; speedup vs baseline: 54.4711x; 1.8379x over previous
//
#include <hip/hip_runtime.h>
#include <stdint.h>

// VectorQuantizer — f32 I/O confirmed. d_in[0]=z [16384,64], d_in[1]=e [8192,64];
// d_out f32: [z_q 16384*64][idx-as-float 16384]. d_ws >= 16MB (round-5 WRITE_SIZE
// evidence: 16.0 MiB recs dispatch).
//
// FROZEN exact numerics (rescore only):
//   sz,se: scalar pairwise-8; c: 4 lanes (k mod 4), mul/add separately rounded,
//   16-chunks ascending, reversed sub-blocks (+12,+8,+4,+0), hadd (q0+q1)+(q2+q3);
//   A=fl(sz+se); d=fl(A-2c); argmin strict-<, first (smallest) index wins.
//
// Round-6: bf16 MFMA prefilter GEMM (17.2 GFLOP @ matrix pipe) computing
// per-(row, 128j-chunk) max of c; rescore exactly rescans every chunk whose max
// is within BAND=1.25e-4 of the row max. Hard capture bound: lattice 7.6e-6 +
// 2 x bf16 dot error 4.3e-5 = 9.4e-5 < BAND.

#define NROWS 16384
#define NE    8192
#define D     64
#define BN    128
#define NCH   (NE / BN)     // 64
#define BAND  1.25e-4f

typedef __attribute__((ext_vector_type(8))) short short8;
typedef __attribute__((ext_vector_type(4))) float f32x4;

// ---------- frozen exact helpers ----------
__device__ __forceinline__ float sumsq_pairwise8(const float* x) {
    float r8[8];
    #pragma unroll
    for (int l = 0; l < 8; ++l) r8[l] = __fmul_rn(x[l], x[l]);
    #pragma unroll
    for (int i = 8; i < 64; i += 8)
        #pragma unroll
        for (int l = 0; l < 8; ++l)
            r8[l] = __fadd_rn(r8[l], __fmul_rn(x[i + l], x[i + l]));
    return __fadd_rn(__fadd_rn(__fadd_rn(r8[0], r8[1]), __fadd_rn(r8[2], r8[3])),
                     __fadd_rn(__fadd_rn(r8[4], r8[5]), __fadd_rn(r8[6], r8[7])));
}

__device__ __forceinline__ float dot_numpy(const float* zr, const float* ef) {
    float q0 = 0.f, q1 = 0.f, q2 = 0.f, q3 = 0.f;
    #pragma unroll
    for (int cc = 0; cc < 4; ++cc) {
        const int b = cc * 16;
        q0 = __fadd_rn(q0, __fmul_rn(zr[b + 12], ef[b + 12]));
        q1 = __fadd_rn(q1, __fmul_rn(zr[b + 13], ef[b + 13]));
        q2 = __fadd_rn(q2, __fmul_rn(zr[b + 14], ef[b + 14]));
        q3 = __fadd_rn(q3, __fmul_rn(zr[b + 15], ef[b + 15]));
        q0 = __fadd_rn(q0, __fmul_rn(zr[b +  8], ef[b +  8]));
        q1 = __fadd_rn(q1, __fmul_rn(zr[b +  9], ef[b +  9]));
        q2 = __fadd_rn(q2, __fmul_rn(zr[b + 10], ef[b + 10]));
        q3 = __fadd_rn(q3, __fmul_rn(zr[b + 11], ef[b + 11]));
        q0 = __fadd_rn(q0, __fmul_rn(zr[b +  4], ef[b +  4]));
        q1 = __fadd_rn(q1, __fmul_rn(zr[b +  5], ef[b +  5]));
        q2 = __fadd_rn(q2, __fmul_rn(zr[b +  6], ef[b +  6]));
        q3 = __fadd_rn(q3, __fmul_rn(zr[b +  7], ef[b +  7]));
        q0 = __fadd_rn(q0, __fmul_rn(zr[b +  0], ef[b +  0]));
        q1 = __fadd_rn(q1, __fmul_rn(zr[b +  1], ef[b +  1]));
        q2 = __fadd_rn(q2, __fmul_rn(zr[b +  2], ef[b +  2]));
        q3 = __fadd_rn(q3, __fmul_rn(zr[b +  3], ef[b +  3]));
    }
    return __fadd_rn(__fadd_rn(q0, q1), __fadd_rn(q2, q3));
}

__device__ __forceinline__ uint32_t bf16rn(float f) {
    union { float f; uint32_t u; } c; c.f = f;
    return (c.u + 0x7FFFu + ((c.u >> 16) & 1u)) >> 16;
}
__device__ __forceinline__ uint32_t pk2(float lo, float hi) {
    return bf16rn(lo) | (bf16rn(hi) << 16);
}

// ---------- phase 0: f32 -> bf16 (RN) ----------
__global__ __launch_bounds__(256)
void vq_convert(const float* __restrict__ z, const float* __restrict__ e,
                uint32_t* __restrict__ zb, uint32_t* __restrict__ eb)
{
    const int i = blockIdx.x * 256 + threadIdx.x;
    const int nz = NROWS * D / 8;            // 131072 (8 floats per thread)
    const int ne = NE * D / 8;               //  65536
    if (i < nz) {
        const float4 a = ((const float4*)z)[i * 2];
        const float4 b = ((const float4*)z)[i * 2 + 1];
        uint4 o; o.x = pk2(a.x, a.y); o.y = pk2(a.z, a.w);
        o.z = pk2(b.x, b.y); o.w = pk2(b.z, b.w);
        ((uint4*)zb)[i] = o;
    } else if (i < nz + ne) {
        const int k = i - nz;
        const float4 a = ((const float4*)e)[k * 2];
        const float4 b = ((const float4*)e)[k * 2 + 1];
        uint4 o; o.x = pk2(a.x, a.y); o.y = pk2(a.z, a.w);
        o.z = pk2(b.x, b.y); o.w = pk2(b.z, b.w);
        ((uint4*)eb)[k] = o;
    }
}

// ---------- phase 1: MFMA GEMM + per-(row,chunk) max ----------
// grid = 64 row-blocks x 32 j-splits; block = 256 thr = 4 waves; wave owns 64 rows.
// Each block handles 2 chunks of 128 j. C/D layout (m89): col=lane&15,
// row=(lane>>4)*4+reg. A: row=lane&15, k=(lane>>4)*8+i (per K-half of 32).
__global__ __launch_bounds__(256)
void vq_scan_mfma(const uint16_t* __restrict__ zb, const uint16_t* __restrict__ eb,
                  float* __restrict__ cmax)
{
    __shared__ uint16_t elds[BN][72];        // 144 B row stride (16B pad): 2-way banks
    __shared__ float    rmld[4][64][20];     // per-wave transpose-reduce scratch

    const int tid  = threadIdx.x;
    const int lane = tid & 63, w = tid >> 6;
    const int mb   = blockIdx.x >> 5;        // 0..63
    const int jb   = blockIdx.x & 31;        // 0..31
    const int row0 = mb * 256 + w * 64;
    const int l15  = lane & 15, l4 = lane >> 4;

    // A-fragments: 64 rows x K=64 in registers (4 M-subtiles x 2 K-halves)
    short8 af[4][2];
    #pragma unroll
    for (int m = 0; m < 4; ++m)
        #pragma unroll
        for (int h = 0; h < 2; ++h)
            af[m][h] = *(const short8*)(zb + (size_t)(row0 + m * 16 + l15) * D + h * 32 + l4 * 8);

    const f32x4 z4 = {0.f, 0.f, 0.f, 0.f};

    #pragma unroll 1
    for (int c = 0; c < 2; ++c) {
        const int j0 = jb * 256 + c * BN;
        {   // cooperative stage: thread does 64 B (row = tid>>1, half = tid&1)
            const int srow = tid >> 1, shalf = tid & 1;
            const uint16_t* sp = eb + (size_t)(j0 + srow) * D + shalf * 32;
            uint16_t* dp = &elds[srow][shalf * 32];
            #pragma unroll
            for (int q = 0; q < 4; ++q)
                *(short8*)(dp + q * 8) = *(const short8*)(sp + q * 8);
        }
        __syncthreads();

        f32x4 rm[4];
        #pragma unroll
        for (int m = 0; m < 4; ++m) rm[m] = {-3.0e38f, -3.0e38f, -3.0e38f, -3.0e38f};

        #pragma unroll 1
        for (int n = 0; n < 8; ++n) {
            const uint16_t* bp = &elds[n * 16 + l15][l4 * 8];
            const short8 b0 = *(const short8*)(bp);        // K-half 0
            const short8 b1 = *(const short8*)(bp + 32);   // K-half 1 (+64 B)
            #pragma unroll
            for (int m = 0; m < 4; ++m) {
                f32x4 acc = __builtin_amdgcn_mfma_f32_16x16x32_bf16(af[m][0], b0, z4, 0, 0, 0);
                acc = __builtin_amdgcn_mfma_f32_16x16x32_bf16(af[m][1], b1, acc, 0, 0, 0);
                #pragma unroll
                for (int r = 0; r < 4; ++r) rm[m][r] = fmaxf(rm[m][r], acc[r]);
            }
        }

        // per-wave transpose-reduce: lane's rm[m][reg] covers row m*16+(lane>>4)*4+reg
        #pragma unroll
        for (int m = 0; m < 4; ++m)
            *(f32x4*)&rmld[w][lane][m * 4] = rm[m];
        // same-wave DS write->read: in-order DS pipe + compiler lgkmcnt
        const int r  = lane;                  // row-within-wave this lane reduces
        const int mm = r >> 4, rg = r & 3, lg = ((r & 15) >> 2) * 16;
        float v = rmld[w][lg][mm * 4 + rg];
        #pragma unroll
        for (int i = 1; i < 16; ++i) v = fmaxf(v, rmld[w][lg + i][mm * 4 + rg]);
        cmax[(size_t)(row0 + r) * NCH + (jb * 2 + c)] = v;
        __syncthreads();   // all waves done with elds before restage
    }
}

// ---------- phase 2: exact rescore of in-band chunks (wave per row) ----------
__global__ __launch_bounds__(256)
void vq_rescore(const float* __restrict__ z, const float* __restrict__ e,
                const float* __restrict__ cmax, float* __restrict__ out)
{
    const int lane = threadIdx.x & 63, w = threadIdx.x >> 6;
    const int row = blockIdx.x * 4 + w;

    const float cm_i = cmax[(size_t)row * NCH + lane];   // 64 lanes = 64 chunks
    float cm = cm_i;
    #pragma unroll
    for (int o = 1; o < 64; o <<= 1) cm = fmaxf(cm, __shfl_xor(cm, o, 64));
    unsigned long long sel = __ballot(cm_i >= cm - BAND);

    float zr[D];
    {
        const float* zp = z + (size_t)row * D;
        #pragma unroll
        for (int k = 0; k < D; k += 4) {
            const float4 v = *(const float4*)(zp + k);
            zr[k] = v.x; zr[k + 1] = v.y; zr[k + 2] = v.z; zr[k + 3] = v.w;
        }
    }
    const float sz = sumsq_pairwise8(zr);

    float bd = 3.0e38f; int bj = 0x7FFFFFFF;
    while (sel) {
        const int ch = __builtin_ctzll(sel); sel &= sel - 1;   // ascending chunks
        float dl[2]; int jl[2];
        #pragma unroll
        for (int s = 0; s < 2; ++s) {
            const int j = ch * BN + lane * 2 + s;
            const float* ep = e + (size_t)j * D;
            float ef[D];
            #pragma unroll
            for (int k = 0; k < D; k += 4) {
                const float4 v = *(const float4*)(ep + k);
                ef[k] = v.x; ef[k + 1] = v.y; ef[k + 2] = v.z; ef[k + 3] = v.w;
            }
            const float se = sumsq_pairwise8(ef);
            const float A  = __fadd_rn(sz, se);                  // fl(sz + se)
            const float cc = dot_numpy(zr, ef);                  // exact numpy order
            dl[s] = __fsub_rn(A, __fadd_rn(cc, cc));             // fl(A - 2c)
            jl[s] = j;
        }
        float d = dl[0]; int j = jl[0];
        if (dl[1] < d) { d = dl[1]; j = jl[1]; }                 // tie keeps smaller j
        #pragma unroll
        for (int o = 1; o < 64; o <<= 1) {
            const float od = __shfl_xor(d, o, 64);
            const int   oj = __shfl_xor(j, o, 64);
            if (od < d || (od == d && oj < j)) { d = od; j = oj; }
        }
        if (d < bd || (d == bd && j < bj)) { bd = d; bj = j; }   // global first-min
    }
    if (lane == 0) out[(size_t)NROWS * D + row] = (float)bj;
}

// ---------- phase 3: z_q = fl(z + fl(e[idx] - z)) ----------
__global__ __launch_bounds__(256)
void vq_zq(const float* __restrict__ z, const float* __restrict__ e,
           float* __restrict__ out)
{
    const size_t m = (size_t)blockIdx.x * 256 + threadIdx.x;
    const int r = (int)(m >> 6), k = (int)(m & 63);
    const int sel = (int)out[(size_t)NROWS * D + r];
    const float zv = z[m];
    const float ev = e[(size_t)sel * D + k];
    out[m] = __fadd_rn(zv, __fsub_rn(ev, zv));
}

extern "C" void kernel_launch(void* const* d_in, const int* in_sizes, int n_in,
                              void* d_out, int out_size, void* d_ws, size_t ws_size,
                              hipStream_t stream)
{
    const float* z = (const float*)d_in[0];
    const float* e = (const float*)d_in[1];
    float* out = (float*)d_out;

    // ws layout: zb bf16 2MB | eb bf16 1MB | chunkmax f32 4MB  (ws >= 16MB confirmed)
    uint16_t* zb = (uint16_t*)d_ws;
    uint16_t* eb = (uint16_t*)((char*)d_ws + (size_t)2 * 1024 * 1024);
    float* cmaxb = (float*)((char*)d_ws + (size_t)3 * 1024 * 1024);

    vq_convert  <<<dim3(768),          dim3(256), 0, stream>>>(z, e, (uint32_t*)zb, (uint32_t*)eb);
    vq_scan_mfma<<<dim3(2048),         dim3(256), 0, stream>>>(zb, eb, cmaxb);
    vq_rescore  <<<dim3(NROWS / 4),    dim3(256), 0, stream>>>(z, e, cmaxb, out);
    vq_zq       <<<dim3(NROWS * D / 256), dim3(256), 0, stream>>>(z, e, out);
}